// Round 3
// baseline (887.283 us; speedup 1.0000x reference)
//
#include <hip/hip_runtime.h>
#include <stdint.h>

typedef __bf16 bf16x8 __attribute__((ext_vector_type(8)));
typedef float f32x4 __attribute__((ext_vector_type(4)));

__device__ __forceinline__ float b2f(unsigned short u){
  unsigned int t = ((unsigned int)u) << 16;
  return __builtin_bit_cast(float, t);
}
__device__ __forceinline__ unsigned short f2b(float f){
  unsigned int x = __builtin_bit_cast(unsigned int, f);
  x = x + 0x7FFFu + ((x >> 16) & 1u);
  return (unsigned short)(x >> 16);
}
// spread 8 bits -> 8 packed bf16 {0.0,1.0} (element j = bit j)
__device__ __forceinline__ void spread8(unsigned int B, unsigned int w[4]){
  unsigned int m = __umul24(B, 0x8001u);   // bits0-7 = B, bits15-22 = B
  w[0] = __umul24(m & 0x00010001u, 0x3F80u);
  w[1] = __umul24(m & 0x00040004u, 0x0FE0u);
  w[2] = __umul24(m & 0x00100010u, 0x03F8u);
  w[3] = __umul24(m & 0x00400040u, 0x00FEu);
}

__global__ void k_zero(int* deg, float* seg, float* cnt){
  int id = blockIdx.x*256 + threadIdx.x;
  if (id < 8192){ deg[id] = 0; seg[id] = 0.f; }
  if (id < 256)  cnt[id] = 0.f;
}

// ---- dtype detection: bf16 even-index u16s have sane exponents; f32 low-halves are noise ----
__global__ void k_detect(const unsigned short* __restrict__ src, int* __restrict__ flag){
  __shared__ int red[256];
  int t = threadIdx.x;
  int c = 0;
  for (int i = t; i < 3200; i += 256){
    unsigned int u = src[2*i];
    int e = (int)((u >> 7) & 0xFF);
    c += (e >= 100 && e <= 127) ? 1 : 0;
  }
  red[t] = c;
  __syncthreads();
  if (t == 0){
    int s = 0;
    for (int i = 0; i < 256; i++) s += red[i];
    flag[0] = (s*2 > 3200) ? 1 : 0;   // 1 = inputs are bf16, 0 = float32
  }
}

// ---- convert a float tensor (either dtype) to canonical bf16 ----
__global__ void k_conv(const void* __restrict__ src, unsigned short* __restrict__ dst,
                       int n, const int* __restrict__ flag){
  int id = blockIdx.x*256 + threadIdx.x;
  if (id < n){
    if (flag[0]) dst[id] = ((const unsigned short*)src)[id];
    else         dst[id] = f2b(((const float*)src)[id]);
  }
}

// ---- pack adjacency into 16x16x32-A-fragment bit layout + degrees ----
// dword (rb16*64 + kgg)*64 + L, byte s, bit j  <->
//   A[row = rb16*16 + (L&15)][col = kgg*128 + s*32 + (L>>4)*8 + j]
__global__ void k_pack(const int* __restrict__ adj, unsigned int* __restrict__ mask3,
                       int* __restrict__ deg){
  int tid = blockIdx.x*256 + threadIdx.x;    // 2,097,152
  int rb  = tid >> 12;                       // [0,512)
  int rem = tid & 4095;
  int kgg = rem >> 6;                        // [0,64)
  int L   = rem & 63;
  int lc = L & 15, q = L >> 4;
  int row = rb*16 + lc;
  const int* arow = adj + (size_t)row*8192 + kgg*128 + q*8;
  unsigned int dw = 0; int pc = 0;
  #pragma unroll
  for (int s=0;s<4;s++){
    const int* p = arow + s*32;
    unsigned int b = 0;
    #pragma unroll
    for (int t=0;t<8;t++) b |= (p[t] > 0 ? 1u : 0u) << t;
    dw |= b << (8*s);
    pc += __popc(b);
  }
  mask3[tid] = dw;
  pc += __shfl_xor(pc, 16);
  pc += __shfl_xor(pc, 32);
  if (q == 0) atomicAdd(deg + row, pc);
}

__global__ void k_inv(const int* __restrict__ deg, float* __restrict__ inv){
  int id = blockIdx.x*256 + threadIdx.x;
  if (id < 8192){
    int d = deg[id];
    inv[id] = d > 0 ? 1.f/(float)d : 0.f;
  }
}

// ---- embedding gather: hf32, hncat h-half, hfrag (16x16x32 B-operand layout) ----
// hfrag[(ks32*2 + nt)*64 + L] elem j = h[ks32*32 + (L>>4)*8 + j][nt*16 + (L&15)]
__global__ void k_embed(const int* __restrict__ af, const void* __restrict__ araw,
                        const int* __restrict__ flag,
                        float* __restrict__ hf32, unsigned short* hncat,
                        uint4* __restrict__ hfrag){
  __shared__ __align__(16) float sh[512];
  int t = threadIdx.x;
  int r = t >> 5, c = t & 31;
  int row = blockIdx.x*16 + r;
  int idx = af[row]*32 + c;
  float f;
  if (flag[0]) f = b2f(((const unsigned short*)araw)[idx]);
  else         f = ((const float*)araw)[idx];
  hf32[row*32 + c] = f;
  hncat[row*64 + c] = f2b(f);
  sh[r*32 + c] = f;
  __syncthreads();
  if (t < 64){
    int nt = t >> 5, Lq = t & 31;
    int ks32 = blockIdx.x >> 1, half = blockIdx.x & 1;
    int col = nt*16 + (Lq & 15);
    int rbase = (Lq >> 4)*8;
    unsigned int w[4];
    #pragma unroll
    for (int p=0;p<4;p++){
      unsigned int lo = f2b(sh[(rbase + 2*p    )*32 + col]);
      unsigned int hi = f2b(sh[(rbase + 2*p + 1)*32 + col]);
      w[p] = lo | (hi << 16);
    }
    hfrag[(ks32*2 + nt)*64 + half*32 + Lq] = make_uint4(w[0],w[1],w[2],w[3]);
  }
}

__global__ void k_bond(const int* __restrict__ bft, const void* __restrict__ braw,
                       const int* __restrict__ flag,
                       unsigned short* __restrict__ outB16, float* __restrict__ outB32){
  int id = blockIdx.x*256 + threadIdx.x;
  int e = id >> 5, c = id & 31;
  int idx = bft[e]*32 + c;
  if (flag[0]) outB16[id] = ((const unsigned short*)braw)[idx];
  else         outB32[id] = ((const float*)braw)[idx];
}

// ---- neigh-sum: A(bits) @ h via 16x16x32 MFMA, K split in 4 chunks ----
__launch_bounds__(256)
__global__ void k_neigh(const unsigned int* __restrict__ mask3, const uint4* __restrict__ hfrag,
                        float* __restrict__ partial){
  int wave = threadIdx.x >> 6, L = threadIdx.x & 63;
  int rb = blockIdx.x*4 + wave;            // [0,512)
  int kc = blockIdx.y;                     // [0,4)
  f32x4 acc0 = {0.f,0.f,0.f,0.f}, acc1 = {0.f,0.f,0.f,0.f};
  const unsigned int* mp = mask3 + (size_t)rb*4096 + (size_t)kc*1024 + L;
  const uint4* bp = hfrag + (size_t)kc*8192 + L;
  for (int g=0; g<16; g++){
    unsigned int mw = mp[g*64];
    #pragma unroll
    for (int s=0; s<4; s++){
      int ks = g*4 + s;                    // local K-step [0,64)
      uint4 b0 = bp[(ks*2    )*64];
      uint4 b1 = bp[(ks*2 + 1)*64];
      union { unsigned int u[4]; bf16x8 v; } afr, bf0, bf1;
      spread8((mw >> (8*s)) & 0xFFu, afr.u);
      bf0.u[0]=b0.x; bf0.u[1]=b0.y; bf0.u[2]=b0.z; bf0.u[3]=b0.w;
      bf1.u[0]=b1.x; bf1.u[1]=b1.y; bf1.u[2]=b1.z; bf1.u[3]=b1.w;
      acc0 = __builtin_amdgcn_mfma_f32_16x16x32_bf16(afr.v, bf0.v, acc0, 0,0,0);
      acc1 = __builtin_amdgcn_mfma_f32_16x16x32_bf16(afr.v, bf1.v, acc1, 0,0,0);
    }
  }
  int q = L >> 4, lc = L & 15;
  float* out = partial + (size_t)kc*262144 + (size_t)rb*512;
  #pragma unroll
  for (int rg=0; rg<4; rg++){
    int rowl = q*4 + rg;                   // m89-verified C/D layout
    out[rowl*32 + lc     ] = acc0[rg];
    out[rowl*32 + 16 + lc] = acc1[rg];
  }
}

__global__ void k_reduce(const float* __restrict__ partial, const float* __restrict__ inv,
                         unsigned short* hncat){
  int id = blockIdx.x*256 + threadIdx.x;   // 262144
  int row = id >> 5, c = id & 31;
  float s = partial[id] + partial[262144 + id] + partial[524288 + id] + partial[786432 + id];
  s *= inv[row];
  hncat[row*64 + 32 + c] = f2b(s);
}

// ---- fused layer: msg GEMM -> LDS -> gi GEMM, gh GEMM, GRU, hfrag repack ----
__launch_bounds__(128)
__global__ void k_layer(unsigned short* hncat,
                        const unsigned short* __restrict__ msgW,
                        const unsigned short* __restrict__ msgb,
                        const unsigned short* __restrict__ wih,
                        const unsigned short* __restrict__ whh,
                        const unsigned short* __restrict__ bih,
                        const unsigned short* __restrict__ bhh,
                        const int* __restrict__ deg,
                        float* hf32,
                        unsigned int* __restrict__ hfrag32,
                        const int* __restrict__ bidx,
                        float* __restrict__ seg, float* __restrict__ cnt,
                        unsigned short* __restrict__ outH16, float* __restrict__ outH32,
                        const int* __restrict__ flag, int last){
  __shared__ __align__(16) unsigned short smsg[2][16][264];
  int w = threadIdx.x >> 6, L = threadIdx.x & 63;
  int q = L >> 4, lc = L & 15;
  int rowbase = (blockIdx.x*2 + w)*16;

  // phase 1: msg = [h|neigh] @ msgW^T + b   (16 x 256)
  f32x4 am[16];
  #pragma unroll
  for (int nt=0;nt<16;nt++){ am[nt][0]=0.f; am[nt][1]=0.f; am[nt][2]=0.f; am[nt][3]=0.f; }
  const unsigned short* arow = hncat + (size_t)(rowbase + lc)*64 + q*8;
  #pragma unroll
  for (int ks=0; ks<2; ks++){
    union { uint4 u; bf16x8 v; } afr;
    afr.u = *(const uint4*)(arow + ks*32);
    #pragma unroll
    for (int nt=0; nt<16; nt++){
      union { uint4 u; bf16x8 v; } bfr;
      bfr.u = *(const uint4*)(msgW + (size_t)(nt*16 + lc)*64 + ks*32 + q*8);
      am[nt] = __builtin_amdgcn_mfma_f32_16x16x32_bf16(afr.v, bfr.v, am[nt], 0,0,0);
    }
  }
  int dg[4];
  #pragma unroll
  for (int rg=0;rg<4;rg++) dg[rg] = deg[rowbase + q*4 + rg];
  #pragma unroll
  for (int nt=0; nt<16; nt++){
    int col = nt*16 + lc;
    float bv = b2f(msgb[col]);
    #pragma unroll
    for (int rg=0; rg<4; rg++){
      float v = am[nt][rg] + bv;
      if (dg[rg] == 0) v = 0.f;
      smsg[w][q*4+rg][col] = f2b(v);
    }
  }
  __syncthreads();   // defensive: guarantee LDS writes visible before reads

  // phase 2+3: gi = msg @ wih^T ; gh = h @ whh^T   (16 x 96 each)
  f32x4 gA[6], hA[6];
  #pragma unroll
  for (int nt=0;nt<6;nt++){ gA[nt][0]=0.f;gA[nt][1]=0.f;gA[nt][2]=0.f;gA[nt][3]=0.f;
                            hA[nt][0]=0.f;hA[nt][1]=0.f;hA[nt][2]=0.f;hA[nt][3]=0.f; }
  #pragma unroll
  for (int ks=0; ks<8; ks++){
    union { uint4 u; bf16x8 v; } afr;
    afr.u = *(const uint4*)(&smsg[w][lc][ks*32 + q*8]);
    #pragma unroll
    for (int nt=0; nt<6; nt++){
      union { uint4 u; bf16x8 v; } bfr;
      bfr.u = *(const uint4*)(wih + (size_t)(nt*16 + lc)*256 + ks*32 + q*8);
      gA[nt] = __builtin_amdgcn_mfma_f32_16x16x32_bf16(afr.v, bfr.v, gA[nt], 0,0,0);
    }
  }
  {
    union { uint4 u; bf16x8 v; } afr;
    afr.u = *(const uint4*)(arow);     // h cols q*8..q*8+8 (K=32)
    #pragma unroll
    for (int nt=0; nt<6; nt++){
      union { uint4 u; bf16x8 v; } bfr;
      bfr.u = *(const uint4*)(whh + (size_t)(nt*16 + lc)*32 + q*8);
      hA[nt] = __builtin_amdgcn_mfma_f32_16x16x32_bf16(afr.v, bfr.v, hA[nt], 0,0,0);
    }
  }

  // phase 4: GRU elementwise (all six gate slices live in this lane) + repack
  int isb = flag[0];
  #pragma unroll
  for (int ci=0; ci<2; ci++){
    int c = ci*16 + lc;
    float b_ir = b2f(bih[c]),    b_hr = b2f(bhh[c]);
    float b_iz = b2f(bih[32+c]), b_hz = b2f(bhh[32+c]);
    float b_in = b2f(bih[64+c]), b_hn = b2f(bhh[64+c]);
    float hn2[4];
    #pragma unroll
    for (int rg=0; rg<4; rg++){
      int row = rowbase + q*4 + rg;
      float ir = gA[ci][rg]   + b_ir, hr = hA[ci][rg]   + b_hr;
      float iz = gA[2+ci][rg] + b_iz, hz = hA[2+ci][rg] + b_hz;
      float in = gA[4+ci][rg] + b_in, hn = hA[4+ci][rg] + b_hn;
      float r = 1.f/(1.f + __expf(-(ir+hr)));
      float z = 1.f/(1.f + __expf(-(iz+hz)));
      float n = tanhf(in + r*hn);
      float h = hf32[(size_t)row*32 + c];
      float hv = (1.f - z)*n + z*h;
      hf32[(size_t)row*32 + c] = hv;
      hncat[(size_t)row*64 + c] = f2b(hv);
      if (last){
        if (isb) outH16[(size_t)row*32 + c] = f2b(hv);
        else     outH32[(size_t)row*32 + c] = hv;
        atomicAdd(seg + bidx[row]*32 + c, hv);
        if (c == 0) atomicAdd(cnt + bidx[row], 1.f);
      }
      hn2[rg] = hv;
    }
    int ks32 = rowbase >> 5;
    int half = (rowbase >> 4) & 1;
    int Lh = (half*2 + (q>>1))*16 + lc;
    int p0 = (q & 1)*2;
    unsigned int w0 = (unsigned int)f2b(hn2[0]) | ((unsigned int)f2b(hn2[1]) << 16);
    unsigned int w1 = (unsigned int)f2b(hn2[2]) | ((unsigned int)f2b(hn2[3]) << 16);
    unsigned int base = (unsigned int)(((ks32*2 + ci)*64 + Lh)*4);
    hfrag32[base + p0    ] = w0;
    hfrag32[base + p0 + 1] = w1;
  }
}

__global__ void k_pool(const float* __restrict__ seg, const float* __restrict__ cnt,
                       const unsigned short* __restrict__ pw, const unsigned short* __restrict__ pb,
                       const int* __restrict__ flag,
                       unsigned short* __restrict__ outG16, float* __restrict__ outG32){
  int g = blockIdx.x, o = threadIdx.x;
  float cv = cnt[g];
  float ic = cv > 0.f ? 1.f/cv : 0.f;
  float s = 0.f;
  #pragma unroll
  for (int c=0;c<32;c++) s += seg[g*32+c]*ic*b2f(pw[o*32+c]);
  s += b2f(pb[o]);
  if (flag[0]) outG16[g*256 + o] = f2b(s);
  else         outG32[g*256 + o] = s;
}

extern "C" void kernel_launch(void* const* d_in, const int* in_sizes, int n_in,
                              void* d_out, int out_size, void* d_ws, size_t ws_size,
                              hipStream_t stream){
  const int* af   = (const int*)d_in[0];
  const int* bft  = (const int*)d_in[1];
  const int* adj  = (const int*)d_in[2];
  const int* bidx = (const int*)d_in[3];

  char* ws = (char*)d_ws;                                    // total ~15.5 MB
  unsigned int*   mask3   = (unsigned int*)(ws + 0);         //  8 MB
  float*          partial = (float*)(ws + 8388608);          //  4 MB
  uint4*          hfrag   = (uint4*)(ws + 12582912);         //  512 KB
  unsigned short* hncat   = (unsigned short*)(ws + 13107200);//  1 MB [h | neigh]
  float*          hf32    = (float*)(ws + 14155776);         //  1 MB
  int*            deg     = (int*)(ws + 15204352);           //  32 KB
  float*          inv     = (float*)(ws + 15237120);         //  32 KB
  float*          seg     = (float*)(ws + 15269888);         //  32 KB
  float*          cnt     = (float*)(ws + 15302656);         //  1 KB
  int*            flag    = (int*)(ws + 15303680);           //  64 B
  unsigned short* cw      = (unsigned short*)(ws + 15303744);//  906 KB canonical bf16 weights

  unsigned short* msgWC  = cw;            // 163840
  unsigned short* msgbC  = cw + 163840;   // 2560
  unsigned short* wihC   = cw + 166400;   // 245760
  unsigned short* whhC   = cw + 412160;   // 30720
  unsigned short* bihC   = cw + 442880;   // 960
  unsigned short* bhhC   = cw + 443840;   // 960
  unsigned short* poolWC = cw + 444800;   // 8192
  unsigned short* poolbC = cw + 452992;   // 256

  unsigned short* out16  = (unsigned short*)d_out;
  float*          out32  = (float*)d_out;

  k_zero  <<<32, 256, 0, stream>>>(deg, seg, cnt);
  k_detect<<<1,  256, 0, stream>>>((const unsigned short*)d_in[4], flag);

  k_conv<<<640,  256, 0, stream>>>(d_in[6],  msgWC,  163840, flag);
  k_conv<<<10,   256, 0, stream>>>(d_in[7],  msgbC,  2560,   flag);
  k_conv<<<960,  256, 0, stream>>>(d_in[8],  wihC,   245760, flag);
  k_conv<<<120,  256, 0, stream>>>(d_in[9],  whhC,   30720,  flag);
  k_conv<<<4,    256, 0, stream>>>(d_in[10], bihC,   960,    flag);
  k_conv<<<4,    256, 0, stream>>>(d_in[11], bhhC,   960,    flag);
  k_conv<<<32,   256, 0, stream>>>(d_in[12], poolWC, 8192,   flag);
  k_conv<<<1,    256, 0, stream>>>(d_in[13], poolbC, 256,    flag);

  k_pack <<<8192, 256, 0, stream>>>(adj, mask3, deg);
  k_inv  <<<32,   256, 0, stream>>>(deg, inv);
  k_embed<<<512,  512, 0, stream>>>(af, d_in[4], flag, hf32, hncat, hfrag);
  k_bond <<<4096, 256, 0, stream>>>(bft, d_in[5], flag, out16 + 262144, out32 + 262144);

  for (int d = 0; d < 10; d++){
    k_neigh <<<dim3(128,4), 256, 0, stream>>>(mask3, hfrag, partial);
    k_reduce<<<1024, 256, 0, stream>>>(partial, inv, hncat);
    k_layer <<<256, 128, 0, stream>>>(hncat,
                                      msgWC + (size_t)d*16384, msgbC + d*256,
                                      wihC  + (size_t)d*24576, whhC  + d*3072,
                                      bihC  + d*96,            bhhC  + d*96,
                                      deg, hf32, (unsigned int*)hfrag,
                                      bidx, seg, cnt, out16, out32,
                                      flag, (d == 9) ? 1 : 0);
  }
  k_pool<<<256, 256, 0, stream>>>(seg, cnt, poolWC, poolbC, flag, out16 + 1310720, out32 + 1310720);
}